// Round 9
// baseline (174.162 us; speedup 1.0000x reference)
//
#include <hip/hip_runtime.h>
#include <hip/hip_bf16.h>

typedef unsigned int u32;
typedef unsigned short u16;
typedef short bf16x8 __attribute__((ext_vector_type(8)));
typedef float f32x4 __attribute__((ext_vector_type(4)));
typedef float f32x2 __attribute__((ext_vector_type(2)));
typedef _Float16 h16x2 __attribute__((ext_vector_type(2)));
typedef u32 u32x4 __attribute__((ext_vector_type(4)));
typedef u32 u32x2 __attribute__((ext_vector_type(2)));

#define LQ 11     // sequence length
#define RPB 8     // batch rows per block
#define NR 88     // real samples per side (8*11)
// proj row = 32 u16 = 64 B = 4 chunks of 16 B; physical chunk = logical ^ (row&3)

// d_ws layout (u16 elements): pre-packed bf16 tables, rebuilt every call
#define EMB_OFF   0         // 10000*16
#define PEMB_OFF  160000    // 16*16
#define H2AW_OFF  160256    // 96*32
#define A2HW_OFF  163328    // 96*32
#define PACK_N    166400    // total u16 elements -> 332800 B

// 1/sqrt(8) * log2(e): folded into Q at pack time so Phase C uses raw v_exp_f32
#define QSCALE 0.5100697191248353f

__device__ __forceinline__ float blo(u32 x) { return __uint_as_float(x << 16); }
__device__ __forceinline__ float bhi(u32 x) { return __uint_as_float(x & 0xFFFF0000u); }
__device__ __forceinline__ float bf1(u16 x) { return __uint_as_float(((u32)x) << 16); }
__device__ __forceinline__ u16 f2b(float f) {
    __hip_bfloat16 h = __float2bfloat16(f);
    return *reinterpret_cast<u16*>(&h);
}
__device__ __forceinline__ u32 pk2(float a, float b) {
    return (u32)f2b(a) | ((u32)f2b(b) << 16);
}
// f16 pack/unpack for the main kernel's proj LDS (f16 > bf16 precision here:
// all projected values are ~1e-2, far inside f16 normal range)
__device__ __forceinline__ u32 pkh2(float a, float b) {
    auto h = __builtin_amdgcn_cvt_pkrtz(a, b);   // v_cvt_pkrtz_f16_f32, 1 inst
    return __builtin_bit_cast(u32, h);
}
__device__ __forceinline__ h16x2 h2c(u32 x) { return __builtin_bit_cast(h16x2, x); }
__device__ __forceinline__ float hf1(u16 x) {
    return (float)__builtin_bit_cast(_Float16, x);
}
__device__ __forceinline__ u16 f2h(float f) {
    return __builtin_bit_cast(u16, (_Float16)f);
}
__device__ __forceinline__ float ex2(float x) {
#if __has_builtin(__builtin_amdgcn_exp2f)
    return __builtin_amdgcn_exp2f(x);            // raw v_exp_f32 (exp2)
#else
    return __expf(x * 0.6931471805599453f);      // exp(x*ln2) == 2^x
#endif
}
// approximate reciprocal (v_rcp_f32, ~1 ulp): cuts the ~30cyc exact-div
// sequence off the per-task critical chain. rcp err ~1e-7 vs 4e-3 tolerance.
__device__ __forceinline__ float rcpf(float x) {
#if __has_builtin(__builtin_amdgcn_rcpf)
    return __builtin_amdgcn_rcpf(x);
#else
    return 1.0f / x;
#endif
}

// DPP cross-lane: VALU-pipe lane exchange, no LDS traffic, no address setup.
// dpp_ctrl must be an IR constant -> template parameter (rocPRIM idiom).
template<int CTRL>
__device__ __forceinline__ float dppf(float x) {
    return __int_as_float(__builtin_amdgcn_update_dpp(
        0, __float_as_int(x), CTRL, 0xF, 0xF, true));
}
// Butterfly sum within each 16-lane row (== shfl_xor 1,2,4,8 over width 16).
__device__ __forceinline__ float qsum16(float v) {
    v += dppf<0xB1>(v);   // quad_perm [1,0,3,2]  (xor 1)
    v += dppf<0x4E>(v);   // quad_perm [2,3,0,1]  (xor 2)
    v += dppf<0x124>(v);  // row_ror:4
    v += dppf<0x128>(v);  // row_ror:8
    return v;
}

// ---------- kernel 1: convert f32 tables -> bf16 in d_ws (trivial, ~5us) ----------
__global__ __launch_bounds__(256)
void pack_tables(const float* __restrict__ emb, const float* __restrict__ pemb,
                 const float* __restrict__ h2a_w, const float* __restrict__ a2h_w,
                 u16* __restrict__ ws)
{
    const int i = blockIdx.x * 256 + threadIdx.x;
    if (i >= PACK_N) return;
    const float* src; int off;
    if (i < PEMB_OFF)      { src = emb;   off = EMB_OFF; }
    else if (i < H2AW_OFF) { src = pemb;  off = PEMB_OFF; }
    else if (i < A2HW_OFF) { src = h2a_w; off = H2AW_OFF; }
    else                   { src = a2h_w; off = A2HW_OFF; }
    ws[i] = f2b(src[i - off]);
}

// ---------- kernel 2: main (v24) --------------------------------------------
// v24 = v22 (best-measured, 90.6us) + the V-TRANSPOSE DS-instruction diet.
// Rationale: across v15-v23 wall time tracks VALU-busy(~45us) + LDS-pipe
// (~37us) + conflicts(~5us) additively; every latency/occupancy/barrier lever
// is falsified. The un-dieted pipe is LDS instruction count. Phase C spent
// 22 ds_read_u16/wave on V (2B per DS slot!). Now Phase B writes V transposed
// into VT[side][r][dim][l] (4 u16 scatter-stores on the 4 V-producing waves),
// and Phase C reads a lane's 11 V values as 3 ds_read_b64 (contiguous,
// 8B-aligned, 24B stride ~2-way banks). Net ~-10 DS inst/wave (-13%).
// proj shrinks to 4 mats (Q/K only): LDS 38976B, still 4 blocks/CU.
__global__ __launch_bounds__(512, 4)
void CrossTeam_v24(const int* __restrict__ home, const int* __restrict__ away,
                   const int* __restrict__ hpos, const int* __restrict__ apos,
                   const u16* __restrict__ wsb,
                   const float* __restrict__ h2a_b,
                   const float* __restrict__ h2a_ow, const float* __restrict__ h2a_ob,
                   const float* __restrict__ a2h_b,
                   const float* __restrict__ a2h_ow, const float* __restrict__ a2h_ob,
                   const float* __restrict__ gw, const float* __restrict__ gb,
                   const float* __restrict__ lnw, const float* __restrict__ lnb,
                   float* __restrict__ out)
{
    // proj: 0=Qh 1=Kh 2=Qa 3=Ka (f16, bias folded, Q pre-scaled,
    // sample-major, 16B chunks XOR-swizzled by row&3)
    __shared__ u16 proj[4][NR * 32];          // 22528 B
    // VT[side][r][dim][l]: V transposed, read as 3 b64 per lane in Phase C
    __shared__ u16 VT[2][RPB][32][12];        // 12288 B
    __shared__ struct {                       //  4096 B (Phase C-D only)
        float obuf[2][RPB][32];
        float ybuf[2][RPB][32];
    } cd;
    __shared__ u32 mraw[2][RPB];              //    64 B   -> 38976 B total

    const int t = threadIdx.x;
    const int b0 = blockIdx.x * RPB;
    const int wave = t >> 6, lane = t & 63;
    const int lq = lane >> 4, lm = lane & 15;  // quad, in-tile index

    // ---- padding masks (wave 7 lanes 48-63), pre-barrier ----
    if (t >= 496) {
        const int k = t - 496; const int side = k >> 3; const int r = k & 7;
        const int* arr = side ? away : home;
        u32 m = 0;
        #pragma unroll
        for (int l = 0; l < LQ; ++l) m |= (u32)(arr[(b0 + r) * LQ + l] == 0) << l;
        mraw[side][r] = m;
    }

    // ---- Phase B: QKV projections via MFMA; ids loaded DIRECT from global ----
    {
        const int side = wave >> 2;            // which x-vectors (0=h, 1=a)
        const int mh = (wave >> 1) & 1;        // M-tile half
        const int nh = wave & 1;               // N-tile half
        // h-vectors: Q from h2a.Wq, K/V from a2h.Wk/Wv; a-vectors vice versa
        const u16* wq_src  = wsb + (side ? A2HW_OFF : H2AW_OFF);
        const u16* wkv_src = wsb + (side ? H2AW_OFF : A2HW_OFF);
        const float* bq_src  = side ? a2h_b : h2a_b;
        const float* bkv_src = side ? h2a_b : a2h_b;
        bf16x8 afrag[3]; float bias[3][4];
        #pragma unroll
        for (int i = 0; i < 3; ++i) {
            const int M = (mh * 3 + i) * 16;
            const u16* wsrc = (M < 32) ? wq_src : wkv_src;
            afrag[i] = *(const bf16x8*)(wsrc + (M + lm) * 32 + lq * 8);
            const float* bs = (M < 32) ? bq_src : bkv_src;
            #pragma unroll
            for (int j = 0; j < 4; ++j) bias[i][j] = bs[M + lq * 4 + j];
        }
        // per-lane id loads: quads 0-1 need player id, quads 2-3 need pos id
        const int* idsrc = (lq < 2) ? (side ? away : home)
                                    : (side ? apos : hpos);
        int ids[3];
        #pragma unroll
        for (int nn = 0; nn < 3; ++nn) {
            const int srow = (nh * 3 + nn) * 16 + lm;
            const int s = srow < NR ? srow : NR - 1;     // cols >=88 discarded at store
            ids[nn] = idsrc[b0 * LQ + s];                // == arr[(b0+r)*LQ+l]
        }
        bf16x8 bfrag[3];
        #pragma unroll
        for (int nn = 0; nn < 3; ++nn) {
            bfrag[nn] = *(const bf16x8*)
                (wsb + ((lq < 2) ? EMB_OFF : PEMB_OFF) + ids[nn] * 16 + (lq & 1) * 8);
        }
        #pragma unroll
        for (int nn = 0; nn < 3; ++nn) {
            const int srow = (nh * 3 + nn) * 16 + lm;
            #pragma unroll
            for (int i = 0; i < 3; ++i) {
                f32x4 acc = { bias[i][0], bias[i][1], bias[i][2], bias[i][3] };
                acc = __builtin_amdgcn_mfma_f32_16x16x32_bf16(afrag[i], bfrag[nn], acc, 0, 0, 0);
                const int mt = mh * 3 + i;                 // 0,1=Q 2,3=K 4,5=V
                const int dimw = (mt & 1) * 16 + lq * 4;   // u16 index within 32
                if (mt < 2) {                               // Q matrices: fold scale
                    acc[0] *= QSCALE; acc[1] *= QSCALE;    // (wave-uniform branch)
                    acc[2] *= QSCALE; acc[3] *= QSCALE;
                }
                if (srow < NR) {
                    if (mt >= 4) {
                        // V: transposed scatter into VT[side][r][dim][l]
                        // r = srow/11 via magic mul (exact for 0..87), l = rem
                        const int rr = (srow * 94) >> 10;
                        const int ll = srow - rr * 11;
                        #pragma unroll
                        for (int j = 0; j < 4; ++j)
                            VT[side][rr][dimw + j][ll] = f2h(acc[j]);
                    } else {
                        const int mat = side * 2 + (mt >> 1);  // Qh,Kh,Qa,Ka
                        const int phys = srow * 32 + ((((dimw >> 3) ^ srow) & 3) << 3) + (dimw & 7);
                        uint2 pk;
                        pk.x = pkh2(acc[0], acc[1]);
                        pk.y = pkh2(acc[2], acc[3]);
                        *(uint2*)&proj[mat][phys] = pk;
                    }
                }
            }
        }
    }
    __syncthreads();   // the ONLY barrier: proj + VT + mraw ready for all waves

    // ---- Phase C: attention + query-mean aggregation, lane = (head, qi) ----
    // Q/K burst (12 b128) + V as 3 b64 from VT (was 11 ds_read_u16). Pins
    // (v22 style) keep the burst from re-serializing. Score in packed f16;
    // exp2 (Q pre-scaled); tree denominator; rcp normalize; per-key qsum16 PV.
    {
        const int hh = lane >> 4;              // head
        const int slot = lane & 15;            // qi slot (>=11 inactive)
        const int qi = slot < 11 ? slot : 10;  // clamped for safe loads
        const int dpv = hh * 8 + (slot & 7);   // PV output dim for this lane
        #pragma unroll
        for (int it = 0; it < 2; ++it) {
            const int task = wave * 2 + it;               // 16 tasks over 8 waves
            const int r = task >> 1, dir = task & 1;      // r == wave; 0: h2a, 1: a2h
            const int qmat = dir ? 2 : 0;                 // Qa : Qh
            const int kmat = dir ? 1 : 3;                 // Kh : Ka
            const int vside = 1 - dir;                    // Va for h2a, Vh for a2h
            const int r11 = r * 11;
            const u32 kvraw = mraw[dir ? 0 : 1][r];       // KV-side padding mask
            const u32 kv = (kvraw == 0x7FFu) ? 0u : kvraw;   // safe_mask
            const u32 qraw = mraw[dir ? 1 : 0][r];        // query-side mask
            const u32 smq = (qraw == 0x7FFu) ? 0u : qraw;
            const u32 vm = (~smq) & 0x7FFu;               // valid queries (never empty)
            const float invc = rcpf((float)__popc(vm));
            const float wqw = (slot < 11 && ((vm >> slot) & 1u)) ? invc : 0.f;
            const int qrow = r11 + qi;

            // ---- burst: 1 qp + 11 kp (b128) + 3 b64 of VT ----
            u32x4 qp = *(const u32x4*)&proj[qmat][qrow * 32 + (((hh ^ qrow) & 3) << 3)];
            u32x4 kp[11];
            #pragma unroll
            for (int kb = 0; kb < 4; ++kb) {
                const int krow0 = r11 + kb;
                const int swz = ((hh ^ krow0) & 3) << 3;
                const u16* kbp = &proj[kmat][krow0 * 32 + swz];
                #pragma unroll
                for (int m = 0; m < 3; ++m) {
                    const int ki = kb + 4 * m;            // compile-time constant
                    if (ki < 11) kp[ki] = *(const u32x4*)(kbp + m * 128);  // +256B imm
                }
            }
            const u16* vt = &VT[vside][r][dpv][0];        // 24B row, 8B-aligned
            u32x2 va = *(const u32x2*)(vt);               // l = 0..3
            u32x2 vb = *(const u32x2*)(vt + 4);           // l = 4..7
            u32x2 vc = *(const u32x2*)(vt + 8);           // l = 8..11
            // pin (v22-measured-best style): keep the burst a burst
            asm volatile("" : "+v"(qp));
            #pragma unroll
            for (int ki = 0; ki < 11; ++ki) asm volatile("" : "+v"(kp[ki]));
            asm volatile("" : "+v"(va));
            asm volatile("" : "+v"(vb));
            asm volatile("" : "+v"(vc));
            const u32 vu[6] = { va[0], va[1], vb[0], vb[1], vc[0], vc[1] };

            // ---- score: register-only packed-f16 dots + exp2
            const h16x2 q0 = h2c(qp[0]), q1 = h2c(qp[1]), q2 = h2c(qp[2]), q3 = h2c(qp[3]);
            float e[11];
            #pragma unroll
            for (int ki = 0; ki < 11; ++ki) {
                h16x2 a2 = q0 * h2c(kp[ki][0]);       // v_pk_mul_f16
                a2 += q1 * h2c(kp[ki][1]);            // v_pk_fma_f16
                a2 += q2 * h2c(kp[ki][2]);
                a2 += q3 * h2c(kp[ki][3]);
                const float s = (float)(a2[0] + a2[1]);
                e[ki] = ((kv >> ki) & 1u) ? 0.f : ex2(s);  // exact 2^-inf=0
            }
            // tree denominator: dep depth 4 instead of 11
            const float sum = (((e[0] + e[1]) + (e[2] + e[3]))
                             + ((e[4] + e[5]) + (e[6] + e[7])))
                            + (((e[8] + e[9]) + e[10]));
            const float rs = wqw * rcpf(fmaxf(sum, 1e-20f));
            // ---- PV: per-key butterfly (DPP, VALU-only), V from registers
            // (v_cvt_f32_f16 with op_sel picks the half: 1 inst per ki)
            float o = 0.f;
            #pragma unroll
            for (int ki = 0; ki < 11; ++ki) {
                const float v = qsum16(e[ki] * rs);
                o += v * (float)h2c(vu[ki >> 1])[ki & 1];
            }
            if (slot < 8) cd.obuf[dir][r][dpv] = o;       // 32 dims per task
        }
    }
    // NO __syncthreads here: obuf[*][r] for r==wave was written by THIS wave;
    // same-wave LDS ordering (compiler lgkmcnt) is sufficient for Phase D.

    // ---- Phase D: out-proj + gate + LayerNorm, per-wave (r = wave) ---------
    // All 64 lanes active: d = lane&31, half = lane>>5 owns 16 of each 32-dot;
    // halves combined with one shfl_xor(32). Dots in f32x2 -> v_pk_fma_f32.
    {
        const int r = wave;
        const int d = lane & 31;
        const int half = lane >> 5;            // 0: chunks 0-3, 1: chunks 4-7
        f32x2 sh = {0.f, 0.f}, sa = {0.f, 0.f};
        {
            const f32x4* w0 = (const f32x4*)(h2a_ow + d * 32) + half * 4;
            const f32x4* w1 = (const f32x4*)(a2h_ow + d * 32) + half * 4;
            const f32x4* o0 = (const f32x4*)&cd.obuf[0][r][0] + half * 4;
            const f32x4* o1 = (const f32x4*)&cd.obuf[1][r][0] + half * 4;
            #pragma unroll
            for (int c = 0; c < 4; ++c) {
                const f32x4 a = o0[c], b = w0[c], p = o1[c], q = w1[c];
                sh += (f32x2){a[0], a[1]} * (f32x2){b[0], b[1]};
                sh += (f32x2){a[2], a[3]} * (f32x2){b[2], b[3]};
                sa += (f32x2){p[0], p[1]} * (f32x2){q[0], q[1]};
                sa += (f32x2){p[2], p[3]} * (f32x2){q[2], q[3]};
            }
        }
        float yh = sh[0] + sh[1], ya = sa[0] + sa[1];
        yh += __shfl_xor(yh, 32);              // combine lane halves
        ya += __shfl_xor(ya, 32);
        yh += h2a_ob[d];  ya += a2h_ob[d];
        if (half == 0) { cd.ybuf[0][r][d] = yh; cd.ybuf[1][r][d] = ya; }
        // gate: half 0 dots ybuf[0].gw[d][0:32]; half 1 dots ybuf[1].gw[d][32:64]
        // (half-1 lanes read half-0's writes: same wave, lockstep + lgkmcnt)
        f32x2 ga = {0.f, 0.f};
        {
            const f32x4* gsrc = (const f32x4*)(gw + d * 64) + half * 8;
            const f32x4* ysrc = (const f32x4*)&cd.ybuf[half][r][0];
            #pragma unroll
            for (int c = 0; c < 8; ++c) {
                const f32x4 a = ysrc[c], b = gsrc[c];
                ga += (f32x2){a[0], a[1]} * (f32x2){b[0], b[1]};
                ga += (f32x2){a[2], a[3]} * (f32x2){b[2], b[3]};
            }
        }
        float acc = ga[0] + ga[1];
        acc += __shfl_xor(acc, 32);            // y0-part + y1-part
        acc += gb[d];
        const float g = rcpf(1.0f + ex2(-acc * 1.4426950408889634f));  // sigmoid
        const float m = g * yh + (1.0f - g) * ya;
        // 32-wide reduction over dims: DPP within 16, one shuffle across halves
        // (lanes 32-63 hold the same d-set 0-31, so they mirror harmlessly)
        float s1 = qsum16(m), s2 = qsum16(m * m);
        s1 += __shfl_xor(s1, 16, 32);
        s2 += __shfl_xor(s2, 16, 32);
        const float mu = s1 * 0.03125f;
        const float var = fmaxf(s2 * 0.03125f - mu * mu, 0.f);
        const float res = (m - mu) * rsqrtf(var + 1e-5f) * lnw[d] + lnb[d];
        if (half == 0) out[(b0 + r) * 32 + d] = res;
    }
}

// ---------- fallback (ws too small): proven v9, byte-identical ----------
__global__ __launch_bounds__(512, 6)
void CrossTeam_v9fb(const int* __restrict__ home, const int* __restrict__ away,
                    const int* __restrict__ hpos, const int* __restrict__ apos,
                    const float* __restrict__ emb, const float* __restrict__ pemb,
                    const float* __restrict__ h2a_w, const float* __restrict__ h2a_b,
                    const float* __restrict__ h2a_ow, const float* __restrict__ h2a_ob,
                    const float* __restrict__ a2h_w, const float* __restrict__ a2h_b,
                    const float* __restrict__ a2h_ow, const float* __restrict__ a2h_ob,
                    const float* __restrict__ gw, const float* __restrict__ gb,
                    const float* __restrict__ lnw, const float* __restrict__ lnb,
                    float* __restrict__ out)
{
    __shared__ u16 proj[6][NR * 32];
    __shared__ union {
        int ptab[2][NR][2];
        struct { float obuf[2][RPB][32]; float ybuf[2][RPB][32]; } cd;
    } u;
    __shared__ u32 mraw[2][RPB];
    const int t = threadIdx.x;
    const int b0 = blockIdx.x * RPB;
    if (t < 176) {
        const int side = t / 88, s = t - side * 88;
        const int r = s / 11, l = s - r * 11;
        const int gi = (b0 + r) * LQ + l;
        u.ptab[side][s][0] = side ? away[gi] : home[gi];
        u.ptab[side][s][1] = side ? apos[gi] : hpos[gi];
    }
    if (t >= 496) {
        const int k = t - 496; const int side = k >> 3; const int r = k & 7;
        const int* arr = side ? away : home;
        u32 m = 0;
        for (int l = 0; l < LQ; ++l) m |= (u32)(arr[(b0 + r) * LQ + l] == 0) << l;
        mraw[side][r] = m;
    }
    __syncthreads();
    const int wave = t >> 6, lane = t & 63;
    const int lq = lane >> 4, lm = lane & 15;
    {
        const int side = wave >> 2, mh = (wave >> 1) & 1, nh = wave & 1;
        const float* wq_src  = side ? a2h_w : h2a_w;
        const float* wkv_src = side ? h2a_w : a2h_w;
        const float* bq_src  = side ? a2h_b : h2a_b;
        const float* bkv_src = side ? h2a_b : a2h_b;
        bf16x8 afrag[3]; float bias[3][4];
        #pragma unroll
        for (int i = 0; i < 3; ++i) {
            const int M = (mh * 3 + i) * 16;
            const float* ws = (M < 32) ? wq_src : wkv_src;
            const float* wp = ws + (M + lm) * 32 + lq * 8;
            const f32x4 a0 = *(const f32x4*)wp;
            const f32x4 a1 = *(const f32x4*)(wp + 4);
            union { bf16x8 v; u32 w[4]; } au;
            au.w[0] = pk2(a0[0], a0[1]); au.w[1] = pk2(a0[2], a0[3]);
            au.w[2] = pk2(a1[0], a1[1]); au.w[3] = pk2(a1[2], a1[3]);
            afrag[i] = au.v;
            const float* bs = (M < 32) ? bq_src : bkv_src;
            #pragma unroll
            for (int j = 0; j < 4; ++j) bias[i][j] = bs[M + lq * 4 + j];
        }
        bf16x8 bfrag[3];
        #pragma unroll
        for (int nn = 0; nn < 3; ++nn) {
            const int srow = (nh * 3 + nn) * 16 + lm;
            const int s = srow < NR ? srow : NR - 1;
            const int id = u.ptab[side][s][lq >> 1];
            const float* gp = ((lq < 2) ? emb : pemb) + id * 16 + (lq & 1) * 8;
            const f32x4 g0 = *(const f32x4*)gp;
            const f32x4 g1 = *(const f32x4*)(gp + 4);
            union { bf16x8 v; u32 w[4]; } bu;
            bu.w[0] = pk2(g0[0], g0[1]); bu.w[1] = pk2(g0[2], g0[3]);
            bu.w[2] = pk2(g1[0], g1[1]); bu.w[3] = pk2(g1[2], g1[3]);
            bfrag[nn] = bu.v;
        }
        #pragma unroll
        for (int nn = 0; nn < 3; ++nn) {
            const int srow = (nh * 3 + nn) * 16 + lm;
            #pragma unroll
            for (int i = 0; i < 3; ++i) {
                f32x4 acc = { bias[i][0], bias[i][1], bias[i][2], bias[i][3] };
                acc = __builtin_amdgcn_mfma_f32_16x16x32_bf16(afrag[i], bfrag[nn], acc, 0, 0, 0);
                const int mt = mh * 3 + i;
                const int mat = side * 3 + (mt >> 1);
                const int dimw = (mt & 1) * 16 + lq * 4;
                if (srow < NR) {
                    const int phys = srow * 32 + ((((dimw >> 3) ^ srow) & 3) << 3) + (dimw & 7);
                    uint2 pk; pk.x = pk2(acc[0], acc[1]); pk.y = pk2(acc[2], acc[3]);
                    *(uint2*)&proj[mat][phys] = pk;
                }
            }
        }
    }
    __syncthreads();
    {
        const int hh = lane >> 4, slot = lane & 15;
        const int qi = slot < 11 ? slot : 10;
        const int dpv = hh * 8 + (slot & 7);
        #pragma unroll
        for (int it = 0; it < 2; ++it) {
            const int task = wave * 2 + it;
            const int r = task >> 1, dir = task & 1;
            const int qmat = dir ? 3 : 0, kmat = dir ? 1 : 4, vmat = dir ? 2 : 5;
            const int r11 = r * 11;
            const u32 kvraw = mraw[dir ? 0 : 1][r];
            const u32 kv = (kvraw == 0x7FFu) ? 0u : kvraw;
            const u32 qraw = mraw[dir ? 1 : 0][r];
            const u32 smq = (qraw == 0x7FFu) ? 0u : qraw;
            const u32 vm = (~smq) & 0x7FFu;
            const float invc = 1.0f / (float)__popc(vm);
            const float wqw = (slot < 11 && ((vm >> slot) & 1u)) ? invc : 0.f;
            const int qrow = r11 + qi;
            const uint4 qp = *(const uint4*)&proj[qmat][qrow * 32 + (((hh ^ qrow) & 3) << 3)];
            float qv[8];
            qv[0]=blo(qp.x); qv[1]=bhi(qp.x); qv[2]=blo(qp.y); qv[3]=bhi(qp.y);
            qv[4]=blo(qp.z); qv[5]=bhi(qp.z); qv[6]=blo(qp.w); qv[7]=bhi(qp.w);
            float e[11]; float sum = 0.f;
            #pragma unroll
            for (int ki = 0; ki < 11; ++ki) {
                const int krow = r11 + ki;
                const uint4 kp = *(const uint4*)&proj[kmat][krow * 32 + (((hh ^ krow) & 3) << 3)];
                float s = qv[0]*blo(kp.x) + qv[1]*bhi(kp.x) + qv[2]*blo(kp.y) + qv[3]*bhi(kp.y)
                        + qv[4]*blo(kp.z) + qv[5]*bhi(kp.z) + qv[6]*blo(kp.w) + qv[7]*bhi(kp.w);
                s *= 0.35355339059327373f;
                e[ki] = ((kv >> ki) & 1u) ? 0.f : __expf(s);
                sum += e[ki];
            }
            const float rs = wqw / fmaxf(sum, 1e-20f);
            float o = 0.f;
            #pragma unroll
            for (int ki = 0; ki < 11; ++ki) {
                float v = e[ki] * rs;
                v += __shfl_xor(v, 1, 16); v += __shfl_xor(v, 2, 16);
                v += __shfl_xor(v, 4, 16); v += __shfl_xor(v, 8, 16);
                const int vrow = r11 + ki;
                o += v * bf1(proj[vmat][vrow * 32 + (((hh ^ vrow) & 3) << 3) + (slot & 7)]);
            }
            if (slot < 8) u.cd.obuf[dir][r][dpv] = o;
        }
    }
    __syncthreads();
    if (t < 256) {
        const int r = t >> 5, d = t & 31;
        float yh = h2a_ob[d];
        const float* wr = h2a_ow + d * 32;
        #pragma unroll
        for (int c = 0; c < 32; ++c) yh += u.cd.obuf[0][r][c] * wr[c];
        float ya = a2h_ob[d];
        wr = a2h_ow + d * 32;
        #pragma unroll
        for (int c = 0; c < 32; ++c) ya += u.cd.obuf[1][r][c] * wr[c];
        u.cd.ybuf[0][r][d] = yh; u.cd.ybuf[1][r][d] = ya;
        float acc = gb[d];
        const float* gr = gw + d * 64;
        #pragma unroll
        for (int c = 0; c < 32; ++c) acc += u.cd.ybuf[0][r][c] * gr[c];
        #pragma unroll
        for (int c = 0; c < 32; ++c) acc += u.cd.ybuf[1][r][c] * gr[32 + c];
        const float g = 1.0f / (1.0f + __expf(-acc));
        const float m = g * yh + (1.0f - g) * ya;
        float s1 = m, s2 = m * m;
        #pragma unroll
        for (int off = 1; off < 32; off <<= 1) {
            s1 += __shfl_xor(s1, off, 32); s2 += __shfl_xor(s2, off, 32);
        }
        const float mu = s1 * 0.03125f;
        const float var = fmaxf(s2 * 0.03125f - mu * mu, 0.f);
        out[(b0 + r) * 32 + d] = (m - mu) * rsqrtf(var + 1e-5f) * lnw[d] + lnb[d];
    }
}

extern "C" void kernel_launch(void* const* d_in, const int* in_sizes, int n_in,
                              void* d_out, int out_size, void* d_ws, size_t ws_size,
                              hipStream_t stream) {
    (void)in_sizes; (void)n_in; (void)out_size;
    if (ws_size >= (size_t)PACK_N * 2) {
        pack_tables<<<(PACK_N + 255) / 256, 256, 0, stream>>>(
            (const float*)d_in[4], (const float*)d_in[5],
            (const float*)d_in[6], (const float*)d_in[10], (u16*)d_ws);
        CrossTeam_v24<<<32768 / RPB, 512, 0, stream>>>(
            (const int*)d_in[0], (const int*)d_in[1], (const int*)d_in[2], (const int*)d_in[3],
            (const u16*)d_ws,
            (const float*)d_in[7], (const float*)d_in[8], (const float*)d_in[9],
            (const float*)d_in[11], (const float*)d_in[12], (const float*)d_in[13],
            (const float*)d_in[14], (const float*)d_in[15], (const float*)d_in[16],
            (const float*)d_in[17], (float*)d_out);
    } else {
        CrossTeam_v9fb<<<32768 / RPB, 512, 0, stream>>>(
            (const int*)d_in[0], (const int*)d_in[1], (const int*)d_in[2], (const int*)d_in[3],
            (const float*)d_in[4], (const float*)d_in[5],
            (const float*)d_in[6], (const float*)d_in[7], (const float*)d_in[8], (const float*)d_in[9],
            (const float*)d_in[10], (const float*)d_in[11], (const float*)d_in[12], (const float*)d_in[13],
            (const float*)d_in[14], (const float*)d_in[15], (const float*)d_in[16], (const float*)d_in[17],
            (float*)d_out);
    }
}

// Round 10
// 163.698 us; speedup vs baseline: 1.0639x; 1.0639x over previous
//
#include <hip/hip_runtime.h>
#include <hip/hip_bf16.h>

typedef unsigned int u32;
typedef unsigned short u16;
typedef short bf16x8 __attribute__((ext_vector_type(8)));
typedef float f32x4 __attribute__((ext_vector_type(4)));
typedef float f32x2 __attribute__((ext_vector_type(2)));
typedef _Float16 h16x2 __attribute__((ext_vector_type(2)));
typedef u32 u32x4 __attribute__((ext_vector_type(4)));

#define LQ 11     // sequence length
#define RPB 16    // batch rows per block (v25: doubled; fixed-cost amortization)
#define NR 176    // real samples per side = 16*11 = 11 exact 16-row MFMA tiles
// proj row = 32 u16 = 64 B = 4 chunks of 16 B; physical chunk = logical ^ (row&3)

// d_ws layout (u16 elements): pre-packed bf16 tables, rebuilt every call
#define EMB_OFF   0         // 10000*16
#define PEMB_OFF  160000    // 16*16
#define H2AW_OFF  160256    // 96*32
#define A2HW_OFF  163328    // 96*32
#define PACK_N    166400    // total u16 elements -> 332800 B

// 1/sqrt(8) * log2(e): folded into Q at pack time so Phase C uses raw v_exp_f32
#define QSCALE 0.5100697191248353f

__device__ __forceinline__ float blo(u32 x) { return __uint_as_float(x << 16); }
__device__ __forceinline__ float bhi(u32 x) { return __uint_as_float(x & 0xFFFF0000u); }
__device__ __forceinline__ float bf1(u16 x) { return __uint_as_float(((u32)x) << 16); }
__device__ __forceinline__ u16 f2b(float f) {
    __hip_bfloat16 h = __float2bfloat16(f);
    return *reinterpret_cast<u16*>(&h);
}
__device__ __forceinline__ u32 pk2(float a, float b) {
    return (u32)f2b(a) | ((u32)f2b(b) << 16);
}
// f16 pack/unpack for the main kernel's proj LDS (f16 > bf16 precision here:
// all projected values are ~1e-2, far inside f16 normal range)
__device__ __forceinline__ u32 pkh2(float a, float b) {
    auto h = __builtin_amdgcn_cvt_pkrtz(a, b);   // v_cvt_pkrtz_f16_f32, 1 inst
    return __builtin_bit_cast(u32, h);
}
__device__ __forceinline__ h16x2 h2c(u32 x) { return __builtin_bit_cast(h16x2, x); }
__device__ __forceinline__ float hf1(u16 x) {
    return (float)__builtin_bit_cast(_Float16, x);
}
__device__ __forceinline__ float ex2(float x) {
#if __has_builtin(__builtin_amdgcn_exp2f)
    return __builtin_amdgcn_exp2f(x);            // raw v_exp_f32 (exp2)
#else
    return __expf(x * 0.6931471805599453f);      // exp(x*ln2) == 2^x
#endif
}
// approximate reciprocal (v_rcp_f32, ~1 ulp): rcp err ~1e-7 vs 4e-3 tolerance.
__device__ __forceinline__ float rcpf(float x) {
#if __has_builtin(__builtin_amdgcn_rcpf)
    return __builtin_amdgcn_rcpf(x);
#else
    return 1.0f / x;
#endif
}

// DPP cross-lane: VALU-pipe lane exchange, no LDS traffic, no address setup.
template<int CTRL>
__device__ __forceinline__ float dppf(float x) {
    return __int_as_float(__builtin_amdgcn_update_dpp(
        0, __float_as_int(x), CTRL, 0xF, 0xF, true));
}
// Butterfly sum within each 16-lane row (== shfl_xor 1,2,4,8 over width 16).
__device__ __forceinline__ float qsum16(float v) {
    v += dppf<0xB1>(v);   // quad_perm [1,0,3,2]  (xor 1)
    v += dppf<0x4E>(v);   // quad_perm [2,3,0,1]  (xor 2)
    v += dppf<0x124>(v);  // row_ror:4
    v += dppf<0x128>(v);  // row_ror:8
    return v;
}

// ---------- kernel 1: convert f32 tables -> bf16 in d_ws (trivial, ~5us) ----------
__global__ __launch_bounds__(256)
void pack_tables(const float* __restrict__ emb, const float* __restrict__ pemb,
                 const float* __restrict__ h2a_w, const float* __restrict__ a2h_w,
                 u16* __restrict__ ws)
{
    const int i = blockIdx.x * 256 + threadIdx.x;
    if (i >= PACK_N) return;
    const float* src; int off;
    if (i < PEMB_OFF)      { src = emb;   off = EMB_OFF; }
    else if (i < H2AW_OFF) { src = pemb;  off = PEMB_OFF; }
    else if (i < A2HW_OFF) { src = h2a_w; off = H2AW_OFF; }
    else                   { src = a2h_w; off = A2HW_OFF; }
    ws[i] = f2b(src[i - off]);
}

// ---------- kernel 2: main (v25) --------------------------------------------
// v25 = v22 (best-measured, 90.6us; v23/v24 variants flat or worse) with the
// last untested axis: WORK DECOMPOSITION. RPB 8 -> 16:
//  - per-sample fixed costs halve: weight afrag/bias loads are per-wave
//    regardless of RPB; one barrier per 16 rows instead of per 8.
//  - Phase B geometry becomes exact: NR=176=11x16 -> no half-wasted N-tile.
//  - Phase C: 4 independent tasks/wave (was 2) -> 2x intra-wave ILP across
//    task boundaries (true independence; no pin games needed for overlap).
//  - LDS 75904B -> 2 blocks/CU (16 waves). Occupancy was exonerated at
//    53-71% flat, so this deliberately re-tests that conclusion too.
__global__ __launch_bounds__(512, 2)
void CrossTeam_v25(const int* __restrict__ home, const int* __restrict__ away,
                   const int* __restrict__ hpos, const int* __restrict__ apos,
                   const u16* __restrict__ wsb,
                   const float* __restrict__ h2a_b,
                   const float* __restrict__ h2a_ow, const float* __restrict__ h2a_ob,
                   const float* __restrict__ a2h_b,
                   const float* __restrict__ a2h_ow, const float* __restrict__ a2h_ob,
                   const float* __restrict__ gw, const float* __restrict__ gb,
                   const float* __restrict__ lnw, const float* __restrict__ lnb,
                   float* __restrict__ out)
{
    // proj: 0=Qh 1=Kh 2=Vh 3=Qa 4=Ka 5=Va (f16, bias folded, Q pre-scaled,
    // sample-major, 16B chunks XOR-swizzled by row&3)
    __shared__ u16 proj[6][NR * 32];          // 67584 B
    __shared__ struct {                       //  8192 B (Phase C-D only)
        float obuf[2][RPB][32];
        float ybuf[2][RPB][32];
    } cd;
    __shared__ u32 mraw[2][RPB];              //   128 B   -> 75904 B total

    const int t = threadIdx.x;
    const int b0 = blockIdx.x * RPB;
    const int wave = t >> 6, lane = t & 63;
    const int lq = lane >> 4, lm = lane & 15;  // quad, in-tile index

    // ---- padding masks (wave 7 lanes 32-63), pre-barrier ----
    if (t >= 480) {
        const int k = t - 480; const int side = k >> 4; const int r = k & 15;
        const int* arr = side ? away : home;
        u32 m = 0;
        #pragma unroll
        for (int l = 0; l < LQ; ++l) m |= (u32)(arr[(b0 + r) * LQ + l] == 0) << l;
        mraw[side][r] = m;
    }

    // ---- Phase B: QKV projections via MFMA; ids loaded DIRECT from global ----
    {
        const int side = wave >> 2;            // which x-vectors (0=h, 1=a)
        const int mh = (wave >> 1) & 1;        // M-tile half
        const int nh = wave & 1;               // N-tile half: tiles nh*6+nn
        // h-vectors: Q from h2a.Wq, K/V from a2h.Wk/Wv; a-vectors vice versa
        const u16* wq_src  = wsb + (side ? A2HW_OFF : H2AW_OFF);
        const u16* wkv_src = wsb + (side ? H2AW_OFF : A2HW_OFF);
        const float* bq_src  = side ? a2h_b : h2a_b;
        const float* bkv_src = side ? h2a_b : a2h_b;
        bf16x8 afrag[3]; float bias[3][4];
        #pragma unroll
        for (int i = 0; i < 3; ++i) {
            const int M = (mh * 3 + i) * 16;
            const u16* wsrc = (M < 32) ? wq_src : wkv_src;
            afrag[i] = *(const bf16x8*)(wsrc + (M + lm) * 32 + lq * 8);
            const float* bs = (M < 32) ? bq_src : bkv_src;
            #pragma unroll
            for (int j = 0; j < 4; ++j) bias[i][j] = bs[M + lq * 4 + j];
        }
        // per-lane id loads: quads 0-1 need player id, quads 2-3 need pos id
        const int* idsrc = (lq < 2) ? (side ? away : home)
                                    : (side ? apos : hpos);
        // N tiles: nt = nh*6 + nn; nh=0 -> tiles 0-5, nh=1 -> tiles 6-10.
        // srow = nt*16+lm <= 175 always: no clamping, no wasted rows.
        #pragma unroll
        for (int nn = 0; nn < 6; ++nn) {
            const int nt = nh * 6 + nn;
            if (nt < 11) {                     // wave-uniform (only skips nh=1,nn=5)
                const int srow = nt * 16 + lm;
                const int id = idsrc[b0 * LQ + srow];
                const bf16x8 bfrag = *(const bf16x8*)
                    (wsb + ((lq < 2) ? EMB_OFF : PEMB_OFF) + id * 16 + (lq & 1) * 8);
                #pragma unroll
                for (int i = 0; i < 3; ++i) {
                    f32x4 acc = { bias[i][0], bias[i][1], bias[i][2], bias[i][3] };
                    acc = __builtin_amdgcn_mfma_f32_16x16x32_bf16(afrag[i], bfrag, acc, 0, 0, 0);
                    const int mt = mh * 3 + i;
                    const int mat = side * 3 + (mt >> 1);      // Q/K/V of this side
                    const int dimw = (mt & 1) * 16 + lq * 4;   // u16 index within 32
                    if (mt < 2) {                               // Q matrices: fold scale
                        acc[0] *= QSCALE; acc[1] *= QSCALE;    // (wave-uniform branch)
                        acc[2] *= QSCALE; acc[3] *= QSCALE;
                    }
                    const int phys = srow * 32 + ((((dimw >> 3) ^ srow) & 3) << 3) + (dimw & 7);
                    uint2 pk;
                    pk.x = pkh2(acc[0], acc[1]);
                    pk.y = pkh2(acc[2], acc[3]);
                    *(uint2*)&proj[mat][phys] = pk;
                }
            }
        }
    }
    __syncthreads();   // the ONLY barrier: proj + mraw ready for all waves

    // ---- Phase C: attention + query-mean aggregation, lane = (head, qi) ----
    // 4 independent tasks per wave (r = wave*2 + (it>>1), dir = it&1): task
    // t+1's LDS burst can issue while task t computes - real ILP, no pins
    // needed for overlap (v22's pins kept: measured-best config). Score in
    // packed f16; exp2 (Q pre-scaled); tree denominator; rcp normalize;
    // per-key qsum16 butterfly PV.
    {
        const int hh = lane >> 4;              // head
        const int slot = lane & 15;            // qi slot (>=11 inactive)
        const int qi = slot < 11 ? slot : 10;  // clamped for safe loads
        const int dpv = hh * 8 + (slot & 7);   // PV output dim for this lane
        #pragma unroll
        for (int it = 0; it < 4; ++it) {
            const int task = wave * 4 + it;               // 32 tasks over 8 waves
            const int r = task >> 1, dir = task & 1;      // r in {2w, 2w+1}
            const int qmat = dir ? 3 : 0;
            const int kmat = dir ? 1 : 4;
            const int vmat = dir ? 2 : 5;
            const int r11 = r * 11;
            const u32 kvraw = mraw[dir ? 0 : 1][r];       // KV-side padding mask
            const u32 kv = (kvraw == 0x7FFu) ? 0u : kvraw;   // safe_mask
            const u32 qraw = mraw[dir ? 1 : 0][r];        // query-side mask
            const u32 smq = (qraw == 0x7FFu) ? 0u : qraw;
            const u32 vm = (~smq) & 0x7FFu;               // valid queries (never empty)
            const float invc = rcpf((float)__popc(vm));
            const float wqw = (slot < 11 && ((vm >> slot) & 1u)) ? invc : 0.f;
            const int qrow = r11 + qi;

            // ---- burst: 1 qp + 11 kp (b128) + 11 vv (u16), then pin ----
            u32x4 qp = *(const u32x4*)&proj[qmat][qrow * 32 + (((hh ^ qrow) & 3) << 3)];
            u32x4 kp[11]; u32 vv[11];
            #pragma unroll
            for (int kb = 0; kb < 4; ++kb) {
                const int krow0 = r11 + kb;
                const int swz = ((hh ^ krow0) & 3) << 3;
                const u16* kbp = &proj[kmat][krow0 * 32 + swz];
                const u16* vbp = &proj[vmat][krow0 * 32 + swz + (slot & 7)];
                #pragma unroll
                for (int m = 0; m < 3; ++m) {
                    const int ki = kb + 4 * m;            // compile-time constant
                    if (ki < 11) {
                        kp[ki] = *(const u32x4*)(kbp + m * 128);  // +256B imm
                        vv[ki] = (u32)vbp[m * 128];
                    }
                }
            }
            // pin (v22-measured-best style): keep the burst a burst
            asm volatile("" : "+v"(qp));
            #pragma unroll
            for (int ki = 0; ki < 11; ++ki) asm volatile("" : "+v"(kp[ki]));
            #pragma unroll
            for (int ki = 0; ki < 11; ++ki) asm volatile("" : "+v"(vv[ki]));

            // ---- score: register-only packed-f16 dots + exp2
            const h16x2 q0 = h2c(qp[0]), q1 = h2c(qp[1]), q2 = h2c(qp[2]), q3 = h2c(qp[3]);
            float e[11];
            #pragma unroll
            for (int ki = 0; ki < 11; ++ki) {
                h16x2 a2 = q0 * h2c(kp[ki][0]);       // v_pk_mul_f16
                a2 += q1 * h2c(kp[ki][1]);            // v_pk_fma_f16
                a2 += q2 * h2c(kp[ki][2]);
                a2 += q3 * h2c(kp[ki][3]);
                const float s = (float)(a2[0] + a2[1]);
                e[ki] = ((kv >> ki) & 1u) ? 0.f : ex2(s);  // exact 2^-inf=0
            }
            // tree denominator: dep depth 4 instead of 11
            const float sum = (((e[0] + e[1]) + (e[2] + e[3]))
                             + ((e[4] + e[5]) + (e[6] + e[7])))
                            + (((e[8] + e[9]) + e[10]));
            const float rs = wqw * rcpf(fmaxf(sum, 1e-20f));
            // ---- PV: per-key butterfly (DPP, VALU-only), register-held V
            float o = 0.f;
            #pragma unroll
            for (int ki = 0; ki < 11; ++ki) {
                const float v = qsum16(e[ki] * rs);
                o += v * hf1((u16)vv[ki]);
            }
            if (slot < 8) cd.obuf[dir][r][dpv] = o;       // 32 dims per task
        }
    }
    // NO __syncthreads here: obuf[*][r] for r in {2w,2w+1} was written by THIS
    // wave; same-wave LDS ordering (compiler lgkmcnt) is sufficient for Phase D.

    // ---- Phase D: out-proj + gate + LayerNorm, per-wave (2 rows per wave) ---
    // All 64 lanes active: d = lane&31, half = lane>>5 owns 16 of each 32-dot;
    // halves combined with one shfl_xor(32). Dots in f32x2 -> v_pk_fma_f32.
    #pragma unroll
    for (int rr = 0; rr < 2; ++rr) {
        const int r = wave * 2 + rr;
        const int d = lane & 31;
        const int half = lane >> 5;            // 0: chunks 0-3, 1: chunks 4-7
        f32x2 sh = {0.f, 0.f}, sa = {0.f, 0.f};
        {
            const f32x4* w0 = (const f32x4*)(h2a_ow + d * 32) + half * 4;
            const f32x4* w1 = (const f32x4*)(a2h_ow + d * 32) + half * 4;
            const f32x4* o0 = (const f32x4*)&cd.obuf[0][r][0] + half * 4;
            const f32x4* o1 = (const f32x4*)&cd.obuf[1][r][0] + half * 4;
            #pragma unroll
            for (int c = 0; c < 4; ++c) {
                const f32x4 a = o0[c], b = w0[c], p = o1[c], q = w1[c];
                sh += (f32x2){a[0], a[1]} * (f32x2){b[0], b[1]};
                sh += (f32x2){a[2], a[3]} * (f32x2){b[2], b[3]};
                sa += (f32x2){p[0], p[1]} * (f32x2){q[0], q[1]};
                sa += (f32x2){p[2], p[3]} * (f32x2){q[2], q[3]};
            }
        }
        float yh = sh[0] + sh[1], ya = sa[0] + sa[1];
        yh += __shfl_xor(yh, 32);              // combine lane halves
        ya += __shfl_xor(ya, 32);
        yh += h2a_ob[d];  ya += a2h_ob[d];
        if (half == 0) { cd.ybuf[0][r][d] = yh; cd.ybuf[1][r][d] = ya; }
        // gate: half 0 dots ybuf[0].gw[d][0:32]; half 1 dots ybuf[1].gw[d][32:64]
        // (half-1 lanes read half-0's writes: same wave, lockstep + lgkmcnt)
        f32x2 ga = {0.f, 0.f};
        {
            const f32x4* gsrc = (const f32x4*)(gw + d * 64) + half * 8;
            const f32x4* ysrc = (const f32x4*)&cd.ybuf[half][r][0];
            #pragma unroll
            for (int c = 0; c < 8; ++c) {
                const f32x4 a = ysrc[c], b = gsrc[c];
                ga += (f32x2){a[0], a[1]} * (f32x2){b[0], b[1]};
                ga += (f32x2){a[2], a[3]} * (f32x2){b[2], b[3]};
            }
        }
        float acc = ga[0] + ga[1];
        acc += __shfl_xor(acc, 32);            // y0-part + y1-part
        acc += gb[d];
        const float g = rcpf(1.0f + ex2(-acc * 1.4426950408889634f));  // sigmoid
        const float m = g * yh + (1.0f - g) * ya;
        // 32-wide reduction over dims: DPP within 16, one shuffle across halves
        // (lanes 32-63 hold the same d-set 0-31, so they mirror harmlessly)
        float s1 = qsum16(m), s2 = qsum16(m * m);
        s1 += __shfl_xor(s1, 16, 32);
        s2 += __shfl_xor(s2, 16, 32);
        const float mu = s1 * 0.03125f;
        const float var = fmaxf(s2 * 0.03125f - mu * mu, 0.f);
        const float res = (m - mu) * rsqrtf(var + 1e-5f) * lnw[d] + lnb[d];
        if (half == 0) out[(b0 + r) * 32 + d] = res;
    }
}

// ---------- fallback (ws too small): proven v9, byte-identical ----------
#define FB_RPB 8
#define FB_NR 88
__global__ __launch_bounds__(512, 6)
void CrossTeam_v9fb(const int* __restrict__ home, const int* __restrict__ away,
                    const int* __restrict__ hpos, const int* __restrict__ apos,
                    const float* __restrict__ emb, const float* __restrict__ pemb,
                    const float* __restrict__ h2a_w, const float* __restrict__ h2a_b,
                    const float* __restrict__ h2a_ow, const float* __restrict__ h2a_ob,
                    const float* __restrict__ a2h_w, const float* __restrict__ a2h_b,
                    const float* __restrict__ a2h_ow, const float* __restrict__ a2h_ob,
                    const float* __restrict__ gw, const float* __restrict__ gb,
                    const float* __restrict__ lnw, const float* __restrict__ lnb,
                    float* __restrict__ out)
{
    __shared__ u16 proj[6][FB_NR * 32];
    __shared__ union {
        int ptab[2][FB_NR][2];
        struct { float obuf[2][FB_RPB][32]; float ybuf[2][FB_RPB][32]; } cd;
    } u;
    __shared__ u32 mraw[2][FB_RPB];
    const int t = threadIdx.x;
    const int b0 = blockIdx.x * FB_RPB;
    if (t < 176) {
        const int side = t / 88, s = t - side * 88;
        const int r = s / 11, l = s - r * 11;
        const int gi = (b0 + r) * LQ + l;
        u.ptab[side][s][0] = side ? away[gi] : home[gi];
        u.ptab[side][s][1] = side ? apos[gi] : hpos[gi];
    }
    if (t >= 496) {
        const int k = t - 496; const int side = k >> 3; const int r = k & 7;
        const int* arr = side ? away : home;
        u32 m = 0;
        for (int l = 0; l < LQ; ++l) m |= (u32)(arr[(b0 + r) * LQ + l] == 0) << l;
        mraw[side][r] = m;
    }
    __syncthreads();
    const int wave = t >> 6, lane = t & 63;
    const int lq = lane >> 4, lm = lane & 15;
    {
        const int side = wave >> 2, mh = (wave >> 1) & 1, nh = wave & 1;
        const float* wq_src  = side ? a2h_w : h2a_w;
        const float* wkv_src = side ? h2a_w : a2h_w;
        const float* bq_src  = side ? a2h_b : h2a_b;
        const float* bkv_src = side ? h2a_b : a2h_b;
        bf16x8 afrag[3]; float bias[3][4];
        #pragma unroll
        for (int i = 0; i < 3; ++i) {
            const int M = (mh * 3 + i) * 16;
            const float* ws = (M < 32) ? wq_src : wkv_src;
            const float* wp = ws + (M + lm) * 32 + lq * 8;
            const f32x4 a0 = *(const f32x4*)wp;
            const f32x4 a1 = *(const f32x4*)(wp + 4);
            union { bf16x8 v; u32 w[4]; } au;
            au.w[0] = pk2(a0[0], a0[1]); au.w[1] = pk2(a0[2], a0[3]);
            au.w[2] = pk2(a1[0], a1[1]); au.w[3] = pk2(a1[2], a1[3]);
            afrag[i] = au.v;
            const float* bs = (M < 32) ? bq_src : bkv_src;
            #pragma unroll
            for (int j = 0; j < 4; ++j) bias[i][j] = bs[M + lq * 4 + j];
        }
        bf16x8 bfrag[3];
        #pragma unroll
        for (int nn = 0; nn < 3; ++nn) {
            const int srow = (nh * 3 + nn) * 16 + lm;
            const int s = srow < FB_NR ? srow : FB_NR - 1;
            const int id = u.ptab[side][s][lq >> 1];
            const float* gp = ((lq < 2) ? emb : pemb) + id * 16 + (lq & 1) * 8;
            const f32x4 g0 = *(const f32x4*)gp;
            const f32x4 g1 = *(const f32x4*)(gp + 4);
            union { bf16x8 v; u32 w[4]; } bu;
            bu.w[0] = pk2(g0[0], g0[1]); bu.w[1] = pk2(g0[2], g0[3]);
            bu.w[2] = pk2(g1[0], g1[1]); bu.w[3] = pk2(g1[2], g1[3]);
            bfrag[nn] = bu.v;
        }
        #pragma unroll
        for (int nn = 0; nn < 3; ++nn) {
            const int srow = (nh * 3 + nn) * 16 + lm;
            #pragma unroll
            for (int i = 0; i < 3; ++i) {
                f32x4 acc = { bias[i][0], bias[i][1], bias[i][2], bias[i][3] };
                acc = __builtin_amdgcn_mfma_f32_16x16x32_bf16(afrag[i], bfrag[nn], acc, 0, 0, 0);
                const int mt = mh * 3 + i;
                const int mat = side * 3 + (mt >> 1);
                const int dimw = (mt & 1) * 16 + lq * 4;
                if (srow < FB_NR) {
                    const int phys = srow * 32 + ((((dimw >> 3) ^ srow) & 3) << 3) + (dimw & 7);
                    uint2 pk; pk.x = pk2(acc[0], acc[1]); pk.y = pk2(acc[2], acc[3]);
                    *(uint2*)&proj[mat][phys] = pk;
                }
            }
        }
    }
    __syncthreads();
    {
        const int hh = lane >> 4, slot = lane & 15;
        const int qi = slot < 11 ? slot : 10;
        const int dpv = hh * 8 + (slot & 7);
        #pragma unroll
        for (int it = 0; it < 2; ++it) {
            const int task = wave * 2 + it;
            const int r = task >> 1, dir = task & 1;
            const int qmat = dir ? 3 : 0, kmat = dir ? 1 : 4, vmat = dir ? 2 : 5;
            const int r11 = r * 11;
            const u32 kvraw = mraw[dir ? 0 : 1][r];
            const u32 kv = (kvraw == 0x7FFu) ? 0u : kvraw;
            const u32 qraw = mraw[dir ? 1 : 0][r];
            const u32 smq = (qraw == 0x7FFu) ? 0u : qraw;
            const u32 vm = (~smq) & 0x7FFu;
            const float invc = 1.0f / (float)__popc(vm);
            const float wqw = (slot < 11 && ((vm >> slot) & 1u)) ? invc : 0.f;
            const int qrow = r11 + qi;
            const uint4 qp = *(const uint4*)&proj[qmat][qrow * 32 + (((hh ^ qrow) & 3) << 3)];
            float qv[8];
            qv[0]=blo(qp.x); qv[1]=bhi(qp.x); qv[2]=blo(qp.y); qv[3]=bhi(qp.y);
            qv[4]=blo(qp.z); qv[5]=bhi(qp.z); qv[6]=blo(qp.w); qv[7]=bhi(qp.w);
            float e[11]; float sum = 0.f;
            #pragma unroll
            for (int ki = 0; ki < 11; ++ki) {
                const int krow = r11 + ki;
                const uint4 kp = *(const uint4*)&proj[kmat][krow * 32 + (((hh ^ krow) & 3) << 3)];
                float s = qv[0]*blo(kp.x) + qv[1]*bhi(kp.x) + qv[2]*blo(kp.y) + qv[3]*bhi(kp.y)
                        + qv[4]*blo(kp.z) + qv[5]*bhi(kp.z) + qv[6]*blo(kp.w) + qv[7]*bhi(kp.w);
                s *= 0.35355339059327373f;
                e[ki] = ((kv >> ki) & 1u) ? 0.f : __expf(s);
                sum += e[ki];
            }
            const float rs = wqw / fmaxf(sum, 1e-20f);
            float o = 0.f;
            #pragma unroll
            for (int ki = 0; ki < 11; ++ki) {
                float v = e[ki] * rs;
                v += __shfl_xor(v, 1, 16); v += __shfl_xor(v, 2, 16);
                v += __shfl_xor(v, 4, 16); v += __shfl_xor(v, 8, 16);
                const int vrow = r11 + ki;
                o += v * bf1(proj[vmat][vrow * 32 + (((hh ^ vrow) & 3) << 3) + (slot & 7)]);
            }
            if (slot < 8) u.cd.obuf[dir][r][dpv] = o;
        }
    }
    __syncthreads();
    if (t < 256) {
        const int r = t >> 5, d = t & 31;
        float yh = h2a_ob[d];
        const float* wr = h2a_ow + d * 32;
        #pragma unroll
        for (int c = 0; c < 32; ++c) yh += u.cd.obuf[0][r][c] * wr[c];
        float ya = a2h_ob[d];
        wr = a2h_ow + d * 32;
        #pragma unroll
        for (int c = 0; c < 32; ++c) ya += u.cd.obuf[1][r][c] * wr[c];
        u.cd.ybuf[0][r][d] = yh; u.cd.ybuf[1][r][d] = ya;
        float acc = gb[d];
        const float* gr = gw + d * 64;
        #pragma unroll
        for (int c = 0; c < 32; ++c) acc += u.cd.ybuf[0][r][c] * gr[c];
        #pragma unroll
        for (int c = 0; c < 32; ++c) acc += u.cd.ybuf[1][r][c] * gr[32 + c];
        const float g = 1.0f / (1.0f + __expf(-acc));
        const float m = g * yh + (1.0f - g) * ya;
        float s1 = m, s2 = m * m;
        #pragma unroll
        for (int off = 1; off < 32; off <<= 1) {
            s1 += __shfl_xor(s1, off, 32); s2 += __shfl_xor(s2, off, 32);
        }
        const float mu = s1 * 0.03125f;
        const float var = fmaxf(s2 * 0.03125f - mu * mu, 0.f);
        out[(b0 + r) * 32 + d] = (m - mu) * rsqrtf(var + 1e-5f) * lnw[d] + lnb[d];
    }
}

extern "C" void kernel_launch(void* const* d_in, const int* in_sizes, int n_in,
                              void* d_out, int out_size, void* d_ws, size_t ws_size,
                              hipStream_t stream) {
    (void)in_sizes; (void)n_in; (void)out_size;
    if (ws_size >= (size_t)PACK_N * 2) {
        pack_tables<<<(PACK_N + 255) / 256, 256, 0, stream>>>(
            (const float*)d_in[4], (const float*)d_in[5],
            (const float*)d_in[6], (const float*)d_in[10], (u16*)d_ws);
        CrossTeam_v25<<<32768 / RPB, 512, 0, stream>>>(
            (const int*)d_in[0], (const int*)d_in[1], (const int*)d_in[2], (const int*)d_in[3],
            (const u16*)d_ws,
            (const float*)d_in[7], (const float*)d_in[8], (const float*)d_in[9],
            (const float*)d_in[11], (const float*)d_in[12], (const float*)d_in[13],
            (const float*)d_in[14], (const float*)d_in[15], (const float*)d_in[16],
            (const float*)d_in[17], (float*)d_out);
    } else {
        CrossTeam_v9fb<<<32768 / FB_RPB, 512, 0, stream>>>(
            (const int*)d_in[0], (const int*)d_in[1], (const int*)d_in[2], (const int*)d_in[3],
            (const float*)d_in[4], (const float*)d_in[5],
            (const float*)d_in[6], (const float*)d_in[7], (const float*)d_in[8], (const float*)d_in[9],
            (const float*)d_in[10], (const float*)d_in[11], (const float*)d_in[12], (const float*)d_in[13],
            (const float*)d_in[14], (const float*)d_in[15], (const float*)d_in[16], (const float*)d_in[17],
            (float*)d_out);
    }
}